// Round 1
// baseline (93.276 us; speedup 1.0000x reference)
//
#include <hip/hip_runtime.h>
#include <stdint.h>

// ============================================================================
// LaneGraphConvLayerShared: NNConv(edge-conditioned) + root + residual + LN
//
// msg[e,f] = sum_{k<16} a[e,k]*(x[src]@W_k)[f] + (x[src]@B_bias)[f]
//          = (A_e @ W2)[f], A_e[k*64+d] = a[e,k]*x[src,d]; slot 16: a=1, rows=b_edge
// Fused per-64-edge-tile MFMA GEMM [64x1088]@[1088x64], bf16 in / f32 acc.
// W2 pre-arranged in MFMA-B-fragment order (prep kernel) -> coalesced 16B/lane
// loads from L2 (139KB). A built on the fly from LDS-staged x_src (gather), a.
// out = base(x@(W_root+W_res)+bias+b_res via MFMA) + atomic scatter of msg,
// then in-place LayerNorm.
// ============================================================================

#define NSLOT 17

typedef short short8 __attribute__((ext_vector_type(8)));
typedef float floatx4 __attribute__((ext_vector_type(4)));

union AFrag { short8 s8; uint32_t u[4]; };

__device__ __forceinline__ uint32_t cvt_pk_bf16(float lo, float hi) {
  uint32_t r;
  asm("v_cvt_pk_bf16_f32 %0, %1, %2" : "=v"(r) : "v"(lo), "v"(hi));
  return r;
}

__device__ __forceinline__ uint16_t f32_to_bf16_bits(float x) {
  uint32_t u = __float_as_uint(x);
  u += 0x7fffu + ((u >> 16) & 1u);
  return (uint16_t)(u >> 16);
}

// ws layout:
//   [0,        139264): W2frag  bf16 [slot17][kstep2][c4][lane64][i8]
//   [139264,   147456): Wsumfrag bf16 [kstep2][c4][lane64][i8]  (W_root+W_res)
//   [147456,   147712): bsum f32 [64]  (bias + b_res)
#define W2FRAG_OFF 0
#define WSUM_OFF   139264
#define BSUM_OFF   147456
#define PREP_TOTAL 73792   // 69632 + 4096 + 64

__global__ __launch_bounds__(256) void prep_kernel(
    const float* __restrict__ W_edge, const float* __restrict__ b_edge,
    const float* __restrict__ W_root, const float* __restrict__ bias,
    const float* __restrict__ W_res,  const float* __restrict__ b_res,
    uint16_t* __restrict__ w2frag, uint16_t* __restrict__ wsumfrag,
    float* __restrict__ bsum) {
  int gid = blockIdx.x * 256 + threadIdx.x;
  if (gid < 69632) {
    int i = gid & 7, l = (gid >> 3) & 63, c = (gid >> 9) & 3;
    int t = (gid >> 11) & 1, s = gid >> 12;
    int d = t * 32 + 8 * (l >> 4) + i;
    int f = c * 16 + (l & 15);
    float v = (s < 16) ? W_edge[s * 4096 + d * 64 + f] : b_edge[d * 64 + f];
    w2frag[gid] = f32_to_bf16_bits(v);
  } else if (gid < 73728) {
    int g = gid - 69632;
    int i = g & 7, l = (g >> 3) & 63, c = (g >> 9) & 3, t = (g >> 11) & 1;
    int d = t * 32 + 8 * (l >> 4) + i;
    int f = c * 16 + (l & 15);
    wsumfrag[g] = f32_to_bf16_bits(W_root[d * 64 + f] + W_res[d * 64 + f]);
  } else if (gid < PREP_TOTAL) {
    int f = gid - 73728;
    bsum[f] = bias[f] + b_res[f];
  }
}

// base: out[n,f] = sum_d x[n,d]*(W_root+W_res)[d,f] + bias[f]+b_res[f]
__global__ __launch_bounds__(256) void base_kernel(
    const float* __restrict__ x, const uint16_t* __restrict__ wsumfrag,
    const float* __restrict__ bsum, float* __restrict__ out, int N) {
  int w = threadIdx.x >> 6, l = threadIdx.x & 63;
  int l16 = l & 15, lq = l >> 4;
  int arow = blockIdx.x * 64 + w * 16 + l16;
  float xv[16];
#pragma unroll
  for (int t = 0; t < 2; ++t)
#pragma unroll
    for (int i = 0; i < 8; ++i)
      xv[t * 8 + i] = (arow < N) ? x[arow * 64 + t * 32 + 8 * lq + i] : 0.0f;
  AFrag A[2];
#pragma unroll
  for (int t = 0; t < 2; ++t)
#pragma unroll
    for (int j = 0; j < 4; ++j)
      A[t].u[j] = cvt_pk_bf16(xv[t * 8 + 2 * j], xv[t * 8 + 2 * j + 1]);
  floatx4 acc[4];
#pragma unroll
  for (int c = 0; c < 4; ++c) acc[c] = (floatx4){0.f, 0.f, 0.f, 0.f};
  const short8* bp = (const short8*)wsumfrag;
#pragma unroll
  for (int t = 0; t < 2; ++t)
#pragma unroll
    for (int c = 0; c < 4; ++c) {
      short8 B = bp[(t * 4 + c) * 64 + l];
      acc[c] = __builtin_amdgcn_mfma_f32_16x16x32_bf16(A[t].s8, B, acc[c], 0, 0, 0);
    }
#pragma unroll
  for (int c = 0; c < 4; ++c) {
    int f = c * 16 + l16;
    float bs = bsum[f];
#pragma unroll
    for (int r = 0; r < 4; ++r) {
      int row = blockIdx.x * 64 + w * 16 + lq * 4 + r;
      if (row < N) out[row * 64 + f] = acc[c][r] + bs;
    }
  }
}

// edge: per-64-edge tile, C[64 edges x 64 f] = A[64x1088]@W2[1088x64], atomic
// scatter into out[dst].
__global__ __launch_bounds__(256) void edge_kernel(
    const float* __restrict__ x, const int* __restrict__ eidx,
    const float* __restrict__ attr, const uint16_t* __restrict__ w2frag,
    float* __restrict__ out, int E) {
  __shared__ float x_lds[64][68];   // pad 68: 2-way-max bank alias on b128 reads
  __shared__ float a_lds[64][17];   // [..][16] = 1.0f (bias slot)
  __shared__ int dst_lds[64];
  int tid = threadIdx.x;
  int tile0 = blockIdx.x * 64;
  int cnt = min(64, E - tile0);
  int row = tid >> 2, q = tid & 3;
  const int* srcp = eidx;
  const int* dstp = eidx + E;
  int sidx = (row < cnt) ? srcp[tile0 + row] : 0;
#pragma unroll
  for (int j = 0; j < 4; ++j) {
    float4 v = make_float4(0.f, 0.f, 0.f, 0.f);
    if (row < cnt) v = *(const float4*)&x[sidx * 64 + q * 16 + j * 4];
    *(float4*)&x_lds[row][q * 16 + j * 4] = v;
  }
  {
    float a0 = 0.f, a1 = 0.f, a2 = 0.f, a3 = 0.f;
    if (row < cnt) {
      float4 v = *(const float4*)&attr[(tile0 + row) * 16 + q * 4];
      a0 = v.x; a1 = v.y; a2 = v.z; a3 = v.w;
    }
    a_lds[row][q * 4 + 0] = a0;
    a_lds[row][q * 4 + 1] = a1;
    a_lds[row][q * 4 + 2] = a2;
    a_lds[row][q * 4 + 3] = a3;
    if (q == 0) a_lds[row][16] = 1.0f;
  }
  if (tid < 64) dst_lds[tid] = (tid < cnt) ? dstp[tile0 + tid] : 0;
  __syncthreads();

  int w = tid >> 6, l = tid & 63;
  int l16 = l & 15, lq = l >> 4;
  int arow = w * 16 + l16;
  float xv[16];
#pragma unroll
  for (int t = 0; t < 2; ++t)
#pragma unroll
    for (int i = 0; i < 8; ++i)
      xv[t * 8 + i] = x_lds[arow][t * 32 + 8 * lq + i];
  floatx4 acc[4];
#pragma unroll
  for (int c = 0; c < 4; ++c) acc[c] = (floatx4){0.f, 0.f, 0.f, 0.f};
  const short8* bp = (const short8*)w2frag;
#pragma unroll 2
  for (int s = 0; s < NSLOT; ++s) {
    float av = a_lds[arow][s];
#pragma unroll
    for (int t = 0; t < 2; ++t) {
      AFrag A;
#pragma unroll
      for (int j = 0; j < 4; ++j)
        A.u[j] = cvt_pk_bf16(av * xv[t * 8 + 2 * j], av * xv[t * 8 + 2 * j + 1]);
#pragma unroll
      for (int c = 0; c < 4; ++c) {
        short8 B = bp[((s * 2 + t) * 4 + c) * 64 + l];
        acc[c] = __builtin_amdgcn_mfma_f32_16x16x32_bf16(A.s8, B, acc[c], 0, 0, 0);
      }
    }
  }
#pragma unroll
  for (int c = 0; c < 4; ++c) {
    int f = c * 16 + l16;
#pragma unroll
    for (int r = 0; r < 4; ++r) {
      int erow = w * 16 + lq * 4 + r;
      if (erow < cnt) atomicAdd(&out[dst_lds[erow] * 64 + f], acc[c][r]);
    }
  }
}

__global__ __launch_bounds__(256) void ln_kernel(
    float* __restrict__ out, const float* __restrict__ gamma,
    const float* __restrict__ beta, int N) {
  int w = threadIdx.x >> 6, l = threadIdx.x & 63;
  int row = blockIdx.x * 4 + w;
  if (row >= N) return;
  float v = out[row * 64 + l];
  float s = v;
#pragma unroll
  for (int m = 32; m >= 1; m >>= 1) s += __shfl_xor(s, m);
  float mu = s * 0.015625f;
  float d = v - mu;
  float q = d * d;
#pragma unroll
  for (int m = 32; m >= 1; m >>= 1) q += __shfl_xor(q, m);
  float var = q * 0.015625f;
  out[row * 64 + l] = d * rsqrtf(var + 1e-5f) * gamma[l] + beta[l];
}

extern "C" void kernel_launch(void* const* d_in, const int* in_sizes, int n_in,
                              void* d_out, int out_size, void* d_ws, size_t ws_size,
                              hipStream_t stream) {
  const float* x      = (const float*)d_in[0];
  const int*   eidx   = (const int*)d_in[1];
  const float* attr   = (const float*)d_in[2];
  const float* W_edge = (const float*)d_in[3];
  const float* b_edge = (const float*)d_in[4];
  const float* W_root = (const float*)d_in[5];
  const float* bias   = (const float*)d_in[6];
  const float* W_res  = (const float*)d_in[7];
  const float* b_res  = (const float*)d_in[8];
  const float* gamma  = (const float*)d_in[9];
  const float* beta   = (const float*)d_in[10];
  int N = in_sizes[0] / 64;
  int E = in_sizes[1] / 2;
  float* out = (float*)d_out;
  uint16_t* w2frag   = (uint16_t*)((char*)d_ws + W2FRAG_OFF);
  uint16_t* wsumfrag = (uint16_t*)((char*)d_ws + WSUM_OFF);
  float*    bsum     = (float*)((char*)d_ws + BSUM_OFF);

  prep_kernel<<<(PREP_TOTAL + 255) / 256, 256, 0, stream>>>(
      W_edge, b_edge, W_root, bias, W_res, b_res, w2frag, wsumfrag, bsum);
  base_kernel<<<(N + 63) / 64, 256, 0, stream>>>(x, wsumfrag, bsum, out, N);
  edge_kernel<<<(E + 63) / 64, 256, 0, stream>>>(x, eidx, attr, w2frag, out, E);
  ln_kernel<<<(N + 3) / 4, 256, 0, stream>>>(out, gamma, beta, N);
}